// Round 6
// baseline (313.587 us; speedup 1.0000x reference)
//
#include <hip/hip_runtime.h>
#include <hip/hip_bf16.h>
#include <stdint.h>

// Problem constants (fixed by reference spec)
#define N_NODES   10000
#define D_FEAT    256
#define E_EDGES   320000
#define ROW_WORDS 313     // ceil(10000/32) bitmap words per row (LDS only)

typedef __attribute__((ext_vector_type(4))) float float4v;  // 4 x f32

__device__ __forceinline__ float bf2f(uint32_t h) {
    union { uint32_t u; float f; } v; v.u = h << 16; return v.f;
}

// ---------------------------------------------------------------------------
// K0: runtime input-encoding detection (rounds 3-5 evidence: x/w = float32,
// edges = int32; detection kept as a cheap tripwire).
//   flags[0] : 1 = x/w are float32, 0 = bf16
//   flags[1] : edge encoding: 0=int32, 1=int64, 2=float32, 3=float64
// ---------------------------------------------------------------------------
__global__ void __launch_bounds__(256)
detect_modes(const uint32_t* __restrict__ xw, const uint32_t* __restrict__ ew,
             uint32_t* __restrict__ flags) {
    __shared__ uint32_t c_lo, c_huge, c_zodd, c_zeven;
    int t = threadIdx.x;
    if (t == 0) { c_lo = 0; c_huge = 0; c_zodd = 0; c_zeven = 0; }
    __syncthreads();
    uint32_t lo = 0, hg = 0, zo = 0, ze = 0;
    for (int i = t; i < 4096; i += 256) {
        uint32_t e = (xw[i] >> 7) & 0xffu;   // bf16-pair: low elem's exponent
        lo += (e >= 96u && e <= 140u);
        uint32_t we = ew[2 * i], wo = ew[2 * i + 1];
        hg += (we >= 0x30000000u) + (wo >= 0x30000000u);
        zo += (wo == 0u);
        ze += (we == 0u);
    }
    atomicAdd(&c_lo, lo);  atomicAdd(&c_huge, hg);
    atomicAdd(&c_zodd, zo); atomicAdd(&c_zeven, ze);
    __syncthreads();
    if (t == 0) {
        flags[0] = (c_lo < 2048u) ? 1u : 0u;            // f32 x/w?
        uint32_t em;
        if (c_huge < 1000u) em = (c_zodd > 2048u) ? 1u : 0u;   // int64 : int32
        else                em = (c_zeven > 2048u) ? 3u : 2u;  // f64  : f32
        flags[1] = em;
    }
}

__device__ __forceinline__ int read_edge_val(const void* __restrict__ ei,
                                             uint32_t mode, int idx) {
    switch (mode) {
        case 0:  return ((const int*)ei)[idx];
        case 1:  return ((const int*)ei)[2 * idx];        // int64 low word
        case 2:  return (int)((const float*)ei)[idx];
        default: return (int)((const double*)ei)[idx];
    }
}

// ---------------------------------------------------------------------------
// K1: per-node raw degree counts (duplicates included; both directions).
// Edge dropped entirely if either endpoint is out of bounds (never scatter OOB).
// ---------------------------------------------------------------------------
__global__ void count_edges(const void* __restrict__ ei,
                            const uint32_t* __restrict__ flags,
                            uint32_t* __restrict__ cnt) {
    int e = blockIdx.x * blockDim.x + threadIdx.x;
    if (e >= E_EDGES) return;
    uint32_t m = flags[1];
    int s = read_edge_val(ei, m, e);
    int d = read_edge_val(ei, m, E_EDGES + e);
    if ((uint32_t)s >= N_NODES || (uint32_t)d >= N_NODES) return;
    atomicAdd(&cnt[s], 1u);
    atomicAdd(&cnt[d], 1u);
}

// ---------------------------------------------------------------------------
// K2: exclusive scan of counts -> off[0..N]. Single block, 256 thr, 40 rows/thr.
// ---------------------------------------------------------------------------
__global__ void __launch_bounds__(256)
scan_offsets(const uint32_t* __restrict__ cnt, uint32_t* __restrict__ off) {
    __shared__ uint32_t sm[256];
    int t = threadIdx.x;
    int r0 = t * 40, r1 = min(r0 + 40, N_NODES);
    uint32_t s = 0;
    for (int r = r0; r < r1; r++) s += cnt[r];
    sm[t] = s; __syncthreads();
    for (int d = 1; d < 256; d <<= 1) {          // Hillis-Steele inclusive
        uint32_t v = (t >= d) ? sm[t - d] : 0;
        __syncthreads();
        sm[t] += v;
        __syncthreads();
    }
    uint32_t run = sm[t] - s;                     // exclusive prefix
    if (t == 0) off[0] = 0;
    for (int r = r0; r < r1; r++) { run += cnt[r]; off[r + 1] = run; }
}

// ---------------------------------------------------------------------------
// K2b: sanity gate + diagnostic code (fires only if >5% edges dropped).
// ---------------------------------------------------------------------------
__global__ void sanity_gate(const uint32_t* __restrict__ off,
                            uint32_t* __restrict__ flags) {
    uint32_t total = off[N_NODES];               // = 2 * kept_edges
    uint32_t ok95 = (total >= 608000u);
    uint32_t D = 1024u + 512u * flags[0] + 128u * flags[1]
               + 64u * ok95 + 32u * (total >= 64000u);
    flags[2] = ok95 ? 0u : 1u;                   // 1 => diagnostic mode
    flags[3] = D;
}

// ---------------------------------------------------------------------------
// K3: cur = off (fill cursors; cnt buffer is reused as cur)
// ---------------------------------------------------------------------------
__global__ void init_cur(const uint32_t* __restrict__ off, uint32_t* __restrict__ cur) {
    int i = blockIdx.x * blockDim.x + threadIdx.x;
    if (i < N_NODES) cur[i] = off[i];
}

// ---------------------------------------------------------------------------
// K4: scatter edges into CSR col lists (duplicates kept; dedup in K5)
// ---------------------------------------------------------------------------
__global__ void fill_edges(const void* __restrict__ ei,
                           const uint32_t* __restrict__ flags,
                           uint32_t* __restrict__ cur, uint32_t* __restrict__ col) {
    int e = blockIdx.x * blockDim.x + threadIdx.x;
    if (e >= E_EDGES) return;
    uint32_t m = flags[1];
    int s = read_edge_val(ei, m, e);
    int d = read_edge_val(ei, m, E_EDGES + e);
    if ((uint32_t)s >= N_NODES || (uint32_t)d >= N_NODES) return;
    col[atomicAdd(&cur[s], 1u)] = (uint32_t)d;
    col[atomicAdd(&cur[d], 1u)] = (uint32_t)s;
}

// ---------------------------------------------------------------------------
// K5: per-row exact dedup via LDS bitmap; compact col in place; deg_u, dinv.
// 320 threads (5 waves): one thread per bitmap word.
// ---------------------------------------------------------------------------
__global__ void __launch_bounds__(320)
dedup_rows(const uint32_t* __restrict__ off, uint32_t* __restrict__ col,
           uint32_t* __restrict__ deg_u, float* __restrict__ dinv) {
    __shared__ uint32_t bm[ROW_WORDS];
    __shared__ uint32_t sc[320];
    int i = blockIdx.x, t = threadIdx.x;
    if (t < ROW_WORDS) bm[t] = 0;
    __syncthreads();
    uint32_t base = off[i], end = off[i + 1];
    for (uint32_t p = base + t; p < end; p += 320) {
        uint32_t j = col[p];
        atomicOr(&bm[j >> 5], 1u << (j & 31));
    }
    __syncthreads();
    uint32_t c = (t < ROW_WORDS) ? __popc(bm[t]) : 0;
    sc[t] = c; __syncthreads();
    for (int d = 1; d < 320; d <<= 1) {          // inclusive scan, 9 steps
        uint32_t v = (t >= d) ? sc[t - d] : 0;
        __syncthreads();
        sc[t] += v;
        __syncthreads();
    }
    uint32_t total = sc[319];
    if (t == 0) {
        deg_u[i] = total;
        dinv[i]  = 1.0f / sqrtf((float)(total + 1u));   // +1 = the added eye
    }
    if (t < ROW_WORDS) {                          // compact set bits in place
        uint32_t bits = bm[t];
        uint32_t p = base + (sc[t] - c);
        while (bits) {
            col[p++] = ((uint32_t)t << 5) | (uint32_t)__builtin_ctz(bits);
            bits &= bits - 1;
        }
    }
}

// ---------------------------------------------------------------------------
// K6: agg_i = f32( dinv_i * ( sum_{j in nbrs(i)} dinv_j * x_j + dinv_i * x_i ) )
// One wave per row; lane owns 4 channels (16B coalesced f32 loads/stores).
// agg goes into d_out as FLOAT32 (round-5 fix: output buffer is f32, per the
// harness contract "reference output f32 -> float*"); K7 runs in place.
// ---------------------------------------------------------------------------
__global__ void __launch_bounds__(128)
spmm_agg(const uint32_t* __restrict__ off, const uint32_t* __restrict__ col,
         const uint32_t* __restrict__ deg_u, const float* __restrict__ dinv,
         const void* __restrict__ x, const uint32_t* __restrict__ flags,
         float* __restrict__ agg) {
    int wave = threadIdx.x >> 6, lane = threadIdx.x & 63;
    int i = blockIdx.x * 2 + wave;
    uint32_t base = off[i], deg = deg_u[i];
    float di = dinv[i];
    float a0, a1, a2, a3;
    if (flags[0]) {                                // ---- float32 inputs ----
        const float* xf = (const float*)x;
        float4v sv = *(const float4v*)(xf + (size_t)i * D_FEAT + lane * 4);
        a0 = di * sv[0]; a1 = di * sv[1]; a2 = di * sv[2]; a3 = di * sv[3];
        for (uint32_t t = 0; t < deg; t++) {
            uint32_t j = col[base + t];
            float dj = dinv[j];
            float4v v = *(const float4v*)(xf + (size_t)j * D_FEAT + lane * 4);
            a0 = fmaf(dj, v[0], a0); a1 = fmaf(dj, v[1], a1);
            a2 = fmaf(dj, v[2], a2); a3 = fmaf(dj, v[3], a3);
        }
    } else {                                       // ---- bf16 inputs ----
        const uint16_t* xb = (const uint16_t*)x;
        uint2 sv = *(const uint2*)(xb + (size_t)i * D_FEAT + lane * 4);
        a0 = di * bf2f(sv.x & 0xffffu); a1 = di * bf2f(sv.x >> 16);
        a2 = di * bf2f(sv.y & 0xffffu); a3 = di * bf2f(sv.y >> 16);
        for (uint32_t t = 0; t < deg; t++) {
            uint32_t j = col[base + t];
            float dj = dinv[j];
            uint2 v = *(const uint2*)(xb + (size_t)j * D_FEAT + lane * 4);
            a0 = fmaf(dj, bf2f(v.x & 0xffffu), a0);
            a1 = fmaf(dj, bf2f(v.x >> 16),     a1);
            a2 = fmaf(dj, bf2f(v.y & 0xffffu), a2);
            a3 = fmaf(dj, bf2f(v.y >> 16),     a3);
        }
    }
    float4v o = { di * a0, di * a1, di * a2, di * a3 };
    *(float4v*)(agg + (size_t)i * D_FEAT + lane * 4) = o;
}

// ---------------------------------------------------------------------------
// K7: in-place band GEMM, VALU fp32: out[band,:] = agg[band,:] @ W.
// 16 rows/block; thread c owns column c. Band staged to LDS (in-place safe).
// a_lds reads are wave-broadcast (conflict-free); W[k][c] reads coalesced.
// ---------------------------------------------------------------------------
__global__ void __launch_bounds__(256)
gemm_valu(float* __restrict__ io, const void* __restrict__ w,
          const uint32_t* __restrict__ flags) {
    __shared__ float a_lds[16 * D_FEAT];
    int c = threadIdx.x;
    int r0 = blockIdx.x * 16;
    for (int idx = c; idx < 16 * D_FEAT; idx += 256)
        a_lds[idx] = io[(size_t)r0 * D_FEAT + idx];
    __syncthreads();

    float acc[16];
    #pragma unroll
    for (int r = 0; r < 16; r++) acc[r] = 0.f;

    if (flags[0]) {                                // ---- float32 weight ----
        const float* wf = (const float*)w;
        #pragma unroll 4
        for (int k = 0; k < D_FEAT; k++) {
            float wk = wf[(size_t)k * D_FEAT + c];
            #pragma unroll
            for (int r = 0; r < 16; r++)
                acc[r] = fmaf(a_lds[r * D_FEAT + k], wk, acc[r]);
        }
    } else {                                       // ---- bf16 weight ----
        const uint16_t* wb = (const uint16_t*)w;
        #pragma unroll 4
        for (int k = 0; k < D_FEAT; k++) {
            float wk = bf2f(wb[(size_t)k * D_FEAT + c]);
            #pragma unroll
            for (int r = 0; r < 16; r++)
                acc[r] = fmaf(a_lds[r * D_FEAT + k], wk, acc[r]);
        }
    }
    #pragma unroll
    for (int r = 0; r < 16; r++)
        io[(size_t)(r0 + r) * D_FEAT + c] = acc[r];
}

// ---------------------------------------------------------------------------
// K8: diagnostic overwrite — only if the sanity gate tripped. out[0] = D,
// rest 0 (f32, exactly representable).
// ---------------------------------------------------------------------------
__global__ void __launch_bounds__(256)
finalize_diag(const uint32_t* __restrict__ flags, float* __restrict__ out) {
    if (flags[2] == 0u) return;
    int idx = blockIdx.x * 256 + threadIdx.x;
    if (idx < N_NODES * D_FEAT)
        out[idx] = (idx == 0) ? (float)flags[3] : 0.f;
}

// ---------------------------------------------------------------------------
extern "C" void kernel_launch(void* const* d_in, const int* in_sizes, int n_in,
                              void* d_out, int out_size, void* d_ws, size_t ws_size,
                              hipStream_t stream) {
    const void* x  = d_in[0];                    // f32 (detected) [N, 256]
    const void* ei = d_in[1];                    // int32 (detected) [2, E]
    const void* w  = d_in[2];                    // f32 (detected) [256, 256]
    float* out = (float*)d_out;                  // FLOAT32 [N, 256]  (round-5 fix)

    // Workspace layout (total 2,855,168 B):
    //   off   @ 0       : (N+1) u32
    //   cur   @ 40960   : N u32   (cnt first, then fill cursors)
    //   degu  @ 81920   : N u32
    //   dinv  @ 122880  : N f32
    //   flags @ 163840  : 4 u32
    //   col   @ 295168  : 2*E u32 (2,560,000)
    uint8_t* ws = (uint8_t*)d_ws;
    uint32_t* off   = (uint32_t*)(ws);
    uint32_t* cur   = (uint32_t*)(ws + 40960);
    uint32_t* degu  = (uint32_t*)(ws + 81920);
    float*    dinv  = (float*)   (ws + 122880);
    uint32_t* flags = (uint32_t*)(ws + 163840);
    uint32_t* col   = (uint32_t*)(ws + 295168);
    if (ws_size < (size_t)295168 + (size_t)2 * E_EDGES * 4) return;  // no OOB ever

    hipMemsetAsync(cur, 0, (size_t)N_NODES * 4, stream);             // cur = cnt
    detect_modes<<<1, 256, 0, stream>>>((const uint32_t*)x, (const uint32_t*)ei, flags);
    count_edges <<<(E_EDGES + 255) / 256, 256, 0, stream>>>(ei, flags, cur);
    scan_offsets<<<1, 256, 0, stream>>>(cur, off);
    sanity_gate <<<1, 1, 0, stream>>>(off, flags);
    init_cur    <<<(N_NODES + 255) / 256, 256, 0, stream>>>(off, cur);
    fill_edges  <<<(E_EDGES + 255) / 256, 256, 0, stream>>>(ei, flags, cur, col);
    dedup_rows  <<<N_NODES, 320, 0, stream>>>(off, col, degu, dinv);
    spmm_agg    <<<N_NODES / 2, 128, 0, stream>>>(off, col, degu, dinv, x, flags, out);
    gemm_valu   <<<N_NODES / 16, 256, 0, stream>>>(out, w, flags);
    finalize_diag<<<(N_NODES * D_FEAT + 255) / 256, 256, 0, stream>>>(flags, out);
}

// Round 7
// 191.480 us; speedup vs baseline: 1.6377x; 1.6377x over previous
//
#include <hip/hip_runtime.h>
#include <hip/hip_bf16.h>
#include <stdint.h>

// Problem constants (fixed by reference spec)
#define N_NODES   10000
#define D_FEAT    256
#define E_EDGES   320000
#define ROW_WORDS 313     // ceil(10000/32) bitmap words per row
#define ROW_STRIDE 320    // padded words per bitmap row (1280 B)
#define LIST_CAP  1024    // per-wave neighbor list capacity (deg ~ Poisson(64))

typedef __attribute__((ext_vector_type(4))) float float4v;  // 4 x f32

__device__ __forceinline__ float bf2f(uint32_t h) {
    union { uint32_t u; float f; } v; v.u = h << 16; return v.f;
}

// ---------------------------------------------------------------------------
// K0: runtime input-encoding detection (round 3-6 evidence: x/w = float32,
// edges = int32; kept as a cheap tripwire).
//   flags[0] : 1 = x/w are float32, 0 = bf16
//   flags[1] : edge encoding: 0=int32, 1=int64, 2=float32, 3=float64
// ---------------------------------------------------------------------------
__global__ void __launch_bounds__(256)
detect_modes(const uint32_t* __restrict__ xw, const uint32_t* __restrict__ ew,
             uint32_t* __restrict__ flags) {
    __shared__ uint32_t c_lo, c_huge, c_zodd, c_zeven;
    int t = threadIdx.x;
    if (t == 0) { c_lo = 0; c_huge = 0; c_zodd = 0; c_zeven = 0; }
    __syncthreads();
    uint32_t lo = 0, hg = 0, zo = 0, ze = 0;
    for (int i = t; i < 4096; i += 256) {
        uint32_t e = (xw[i] >> 7) & 0xffu;
        lo += (e >= 96u && e <= 140u);
        uint32_t we = ew[2 * i], wo = ew[2 * i + 1];
        hg += (we >= 0x30000000u) + (wo >= 0x30000000u);
        zo += (wo == 0u);
        ze += (we == 0u);
    }
    atomicAdd(&c_lo, lo);  atomicAdd(&c_huge, hg);
    atomicAdd(&c_zodd, zo); atomicAdd(&c_zeven, ze);
    __syncthreads();
    if (t == 0) {
        flags[0] = (c_lo < 2048u) ? 1u : 0u;
        uint32_t em;
        if (c_huge < 1000u) em = (c_zodd > 2048u) ? 1u : 0u;   // int64 : int32
        else                em = (c_zeven > 2048u) ? 3u : 2u;  // f64  : f32
        flags[1] = em;
    }
}

__device__ __forceinline__ int read_edge_val(const void* __restrict__ ei,
                                             uint32_t mode, int idx) {
    switch (mode) {
        case 0:  return ((const int*)ei)[idx];
        case 1:  return ((const int*)ei)[2 * idx];        // int64 low word
        case 2:  return (int)((const float*)ei)[idx];
        default: return (int)((const double*)ei)[idx];
    }
}

// ===========================================================================
// ============ PRIMARY PLAN: global N x N bitmap (ws >= ~12.9 MB) ===========
// ===========================================================================

// ---------------------------------------------------------------------------
// B1: scatter edges into the bitmap (exact dedup via bits; symmetric).
// OOB endpoints dropped (never scatter out of bounds).
// ---------------------------------------------------------------------------
__global__ void scatter_edges(const void* __restrict__ ei,
                              const uint32_t* __restrict__ flags,
                              uint32_t* __restrict__ bitmap) {
    int e = blockIdx.x * blockDim.x + threadIdx.x;
    if (e >= E_EDGES) return;
    uint32_t m = flags[1];
    int s = read_edge_val(ei, m, e);
    int d = read_edge_val(ei, m, E_EDGES + e);
    if ((uint32_t)s >= N_NODES || (uint32_t)d >= N_NODES) return;
    atomicOr(&bitmap[(size_t)s * ROW_STRIDE + (d >> 5)], 1u << (d & 31));
    atomicOr(&bitmap[(size_t)d * ROW_STRIDE + (s >> 5)], 1u << (s & 31));
}

// ---------------------------------------------------------------------------
// B2: dinv_i = 1/sqrt(popcount(row_i) + 1). One wave per row (4 rows/block).
// Coalesced strided reads; shfl butterfly reduce (no barriers).
// ---------------------------------------------------------------------------
__global__ void __launch_bounds__(256)
popc_dinv(const uint32_t* __restrict__ bitmap, float* __restrict__ dinv) {
    int wv = threadIdx.x >> 6, lane = threadIdx.x & 63;
    int i = blockIdx.x * 4 + wv;
    const uint32_t* rb = bitmap + (size_t)i * ROW_STRIDE;
    int pop = 0;
    #pragma unroll
    for (int k = 0; k < 5; k++) {
        int w = lane + 64 * k;
        if (w < ROW_WORDS) pop += __popc(rb[w]);
    }
    #pragma unroll
    for (int off = 32; off > 0; off >>= 1) pop += __shfl_xor(pop, off, 64);
    if (lane == 0) dinv[i] = 1.0f / sqrtf((float)(pop + 1));
}

// ---------------------------------------------------------------------------
// B3: aggregation. One wave per row (4 rows / 256-thr block).
// Phase 1: expand row bitmap -> wave-local LDS index list (shfl scan, no
//          barriers; wave-synchronous LDS write->read is ordered).
// Phase 2: gather loop, UNROLL 4 with 4 independent accumulator sets so
//          4 x 1KB gathers are in flight per wave (the round-6 spmm was
//          latency-bound at 1 outstanding gather: VALUBusy 13%, HBM 15%).
// agg_i = dinv_i * ( sum_{j in bits(row_i)} dinv_j * x_j + dinv_i * x_i )
// (self-edge bit + the unconditional +I term reproduce diag = 2 exactly.)
// ---------------------------------------------------------------------------
__global__ void __launch_bounds__(256)
spmm_bitmap(const uint32_t* __restrict__ bitmap, const float* __restrict__ dinv,
            const void* __restrict__ x, const uint32_t* __restrict__ flags,
            float* __restrict__ agg) {
    __shared__ __align__(16) uint32_t lists[4][LIST_CAP];   // 16 KB
    int wv = threadIdx.x >> 6, lane = threadIdx.x & 63;
    int i = blockIdx.x * 4 + wv;
    uint32_t* list = lists[wv];
    const uint32_t* rb = bitmap + (size_t)i * ROW_STRIDE;

    // ---- Phase 1: bitmap -> index list ----
    uint32_t wbits[5]; int tot = 0;
    #pragma unroll
    for (int k = 0; k < 5; k++) {
        int w = lane + 64 * k;
        uint32_t b = (w < ROW_WORDS) ? rb[w] : 0u;
        wbits[k] = b;
        tot += __popc(b);
    }
    int incl = tot;
    #pragma unroll
    for (int off = 1; off < 64; off <<= 1) {
        int v = __shfl_up(incl, off, 64);
        if (lane >= off) incl += v;
    }
    uint32_t p = (uint32_t)(incl - tot);
    uint32_t deg = (uint32_t)__shfl(incl, 63, 64);
    #pragma unroll
    for (int k = 0; k < 5; k++) {
        uint32_t bits = wbits[k];
        uint32_t base = (uint32_t)(lane + 64 * k) << 5;
        while (bits) {
            if (p < LIST_CAP) list[p] = base + (uint32_t)__builtin_ctz(bits);
            p++;
            bits &= bits - 1;
        }
    }
    if (deg > LIST_CAP) deg = LIST_CAP;          // safety clamp (never expected)
    // wave-synchronous: compiler inserts lgkmcnt before the reads below

    // ---- Phase 2: gather ----
    float di = dinv[i];
    float4v z = {0.f, 0.f, 0.f, 0.f};
    float4v acc0 = z, acc1 = z, acc2 = z, acc3 = z;
    uint32_t t4 = deg & ~3u;
    if (flags[0]) {                                // ---- float32 x ----
        const float* xf = (const float*)x;
        float4v sv = *(const float4v*)(xf + (size_t)i * D_FEAT + lane * 4);
        for (uint32_t t = 0; t < t4; t += 4) {
            uint4 jv = *(const uint4*)&list[t];    // LDS broadcast (same addr)
            float d0 = dinv[jv.x], d1 = dinv[jv.y], d2 = dinv[jv.z], d3 = dinv[jv.w];
            float4v v0 = *(const float4v*)(xf + (size_t)jv.x * D_FEAT + lane * 4);
            float4v v1 = *(const float4v*)(xf + (size_t)jv.y * D_FEAT + lane * 4);
            float4v v2 = *(const float4v*)(xf + (size_t)jv.z * D_FEAT + lane * 4);
            float4v v3 = *(const float4v*)(xf + (size_t)jv.w * D_FEAT + lane * 4);
            acc0 += d0 * v0; acc1 += d1 * v1; acc2 += d2 * v2; acc3 += d3 * v3;
        }
        for (uint32_t t = t4; t < deg; t++) {
            uint32_t j = list[t];
            acc0 += dinv[j] * (*(const float4v*)(xf + (size_t)j * D_FEAT + lane * 4));
        }
        float4v acc = (acc0 + acc1) + (acc2 + acc3) + di * sv;
        *(float4v*)(agg + (size_t)i * D_FEAT + lane * 4) = di * acc;
    } else {                                       // ---- bf16 x ----
        const uint16_t* xb = (const uint16_t*)x;
        uint2 sv = *(const uint2*)(xb + (size_t)i * D_FEAT + lane * 4);
        float4v svf = { bf2f(sv.x & 0xffffu), bf2f(sv.x >> 16),
                        bf2f(sv.y & 0xffffu), bf2f(sv.y >> 16) };
        for (uint32_t t = 0; t < deg; t++) {
            uint32_t j = list[t];
            float dj = dinv[j];
            uint2 v = *(const uint2*)(xb + (size_t)j * D_FEAT + lane * 4);
            float4v vf = { bf2f(v.x & 0xffffu), bf2f(v.x >> 16),
                           bf2f(v.y & 0xffffu), bf2f(v.y >> 16) };
            acc0 += dj * vf;
        }
        float4v acc = acc0 + di * svf;
        *(float4v*)(agg + (size_t)i * D_FEAT + lane * 4) = di * acc;
    }
}

// ===========================================================================
// ================== FALLBACK PLAN: CSR build (small ws) ====================
// (verbatim from the passing round-6 kernel)
// ===========================================================================

__global__ void count_edges(const void* __restrict__ ei,
                            const uint32_t* __restrict__ flags,
                            uint32_t* __restrict__ cnt) {
    int e = blockIdx.x * blockDim.x + threadIdx.x;
    if (e >= E_EDGES) return;
    uint32_t m = flags[1];
    int s = read_edge_val(ei, m, e);
    int d = read_edge_val(ei, m, E_EDGES + e);
    if ((uint32_t)s >= N_NODES || (uint32_t)d >= N_NODES) return;
    atomicAdd(&cnt[s], 1u);
    atomicAdd(&cnt[d], 1u);
}

__global__ void __launch_bounds__(256)
scan_offsets(const uint32_t* __restrict__ cnt, uint32_t* __restrict__ off) {
    __shared__ uint32_t sm[256];
    int t = threadIdx.x;
    int r0 = t * 40, r1 = min(r0 + 40, N_NODES);
    uint32_t s = 0;
    for (int r = r0; r < r1; r++) s += cnt[r];
    sm[t] = s; __syncthreads();
    for (int d = 1; d < 256; d <<= 1) {
        uint32_t v = (t >= d) ? sm[t - d] : 0;
        __syncthreads();
        sm[t] += v;
        __syncthreads();
    }
    uint32_t run = sm[t] - s;
    if (t == 0) off[0] = 0;
    for (int r = r0; r < r1; r++) { run += cnt[r]; off[r + 1] = run; }
}

__global__ void init_cur(const uint32_t* __restrict__ off, uint32_t* __restrict__ cur) {
    int i = blockIdx.x * blockDim.x + threadIdx.x;
    if (i < N_NODES) cur[i] = off[i];
}

__global__ void fill_edges(const void* __restrict__ ei,
                           const uint32_t* __restrict__ flags,
                           uint32_t* __restrict__ cur, uint32_t* __restrict__ col) {
    int e = blockIdx.x * blockDim.x + threadIdx.x;
    if (e >= E_EDGES) return;
    uint32_t m = flags[1];
    int s = read_edge_val(ei, m, e);
    int d = read_edge_val(ei, m, E_EDGES + e);
    if ((uint32_t)s >= N_NODES || (uint32_t)d >= N_NODES) return;
    col[atomicAdd(&cur[s], 1u)] = (uint32_t)d;
    col[atomicAdd(&cur[d], 1u)] = (uint32_t)s;
}

__global__ void __launch_bounds__(320)
dedup_rows(const uint32_t* __restrict__ off, uint32_t* __restrict__ col,
           uint32_t* __restrict__ deg_u, float* __restrict__ dinv) {
    __shared__ uint32_t bm[ROW_WORDS];
    __shared__ uint32_t sc[320];
    int i = blockIdx.x, t = threadIdx.x;
    if (t < ROW_WORDS) bm[t] = 0;
    __syncthreads();
    uint32_t base = off[i], end = off[i + 1];
    for (uint32_t p = base + t; p < end; p += 320) {
        uint32_t j = col[p];
        atomicOr(&bm[j >> 5], 1u << (j & 31));
    }
    __syncthreads();
    uint32_t c = (t < ROW_WORDS) ? __popc(bm[t]) : 0;
    sc[t] = c; __syncthreads();
    for (int d = 1; d < 320; d <<= 1) {
        uint32_t v = (t >= d) ? sc[t - d] : 0;
        __syncthreads();
        sc[t] += v;
        __syncthreads();
    }
    uint32_t total = sc[319];
    if (t == 0) {
        deg_u[i] = total;
        dinv[i]  = 1.0f / sqrtf((float)(total + 1u));
    }
    if (t < ROW_WORDS) {
        uint32_t bits = bm[t];
        uint32_t p = base + (sc[t] - c);
        while (bits) {
            col[p++] = ((uint32_t)t << 5) | (uint32_t)__builtin_ctz(bits);
            bits &= bits - 1;
        }
    }
}

__global__ void __launch_bounds__(128)
spmm_agg(const uint32_t* __restrict__ off, const uint32_t* __restrict__ col,
         const uint32_t* __restrict__ deg_u, const float* __restrict__ dinv,
         const void* __restrict__ x, const uint32_t* __restrict__ flags,
         float* __restrict__ agg) {
    int wave = threadIdx.x >> 6, lane = threadIdx.x & 63;
    int i = blockIdx.x * 2 + wave;
    uint32_t base = off[i], deg = deg_u[i];
    float di = dinv[i];
    float a0, a1, a2, a3;
    if (flags[0]) {
        const float* xf = (const float*)x;
        float4v sv = *(const float4v*)(xf + (size_t)i * D_FEAT + lane * 4);
        a0 = di * sv[0]; a1 = di * sv[1]; a2 = di * sv[2]; a3 = di * sv[3];
        for (uint32_t t = 0; t < deg; t++) {
            uint32_t j = col[base + t];
            float dj = dinv[j];
            float4v v = *(const float4v*)(xf + (size_t)j * D_FEAT + lane * 4);
            a0 = fmaf(dj, v[0], a0); a1 = fmaf(dj, v[1], a1);
            a2 = fmaf(dj, v[2], a2); a3 = fmaf(dj, v[3], a3);
        }
    } else {
        const uint16_t* xb = (const uint16_t*)x;
        uint2 sv = *(const uint2*)(xb + (size_t)i * D_FEAT + lane * 4);
        a0 = di * bf2f(sv.x & 0xffffu); a1 = di * bf2f(sv.x >> 16);
        a2 = di * bf2f(sv.y & 0xffffu); a3 = di * bf2f(sv.y >> 16);
        for (uint32_t t = 0; t < deg; t++) {
            uint32_t j = col[base + t];
            float dj = dinv[j];
            uint2 v = *(const uint2*)(xb + (size_t)j * D_FEAT + lane * 4);
            a0 = fmaf(dj, bf2f(v.x & 0xffffu), a0);
            a1 = fmaf(dj, bf2f(v.x >> 16),     a1);
            a2 = fmaf(dj, bf2f(v.y & 0xffffu), a2);
            a3 = fmaf(dj, bf2f(v.y >> 16),     a3);
        }
    }
    float4v o = { di * a0, di * a1, di * a2, di * a3 };
    *(float4v*)(agg + (size_t)i * D_FEAT + lane * 4) = o;
}

// ===========================================================================
// Shared epilogue GEMM (both plans): out[band,:] = agg[band,:] @ W, in place.
// ===========================================================================
__global__ void __launch_bounds__(256)
gemm_valu(float* __restrict__ io, const void* __restrict__ w,
          const uint32_t* __restrict__ flags) {
    __shared__ float a_lds[16 * D_FEAT];
    int c = threadIdx.x;
    int r0 = blockIdx.x * 16;
    for (int idx = c; idx < 16 * D_FEAT; idx += 256)
        a_lds[idx] = io[(size_t)r0 * D_FEAT + idx];
    __syncthreads();

    float acc[16];
    #pragma unroll
    for (int r = 0; r < 16; r++) acc[r] = 0.f;

    if (flags[0]) {
        const float* wf = (const float*)w;
        #pragma unroll 4
        for (int k = 0; k < D_FEAT; k++) {
            float wk = wf[(size_t)k * D_FEAT + c];
            #pragma unroll
            for (int r = 0; r < 16; r++)
                acc[r] = fmaf(a_lds[r * D_FEAT + k], wk, acc[r]);
        }
    } else {
        const uint16_t* wb = (const uint16_t*)w;
        #pragma unroll 4
        for (int k = 0; k < D_FEAT; k++) {
            float wk = bf2f(wb[(size_t)k * D_FEAT + c]);
            #pragma unroll
            for (int r = 0; r < 16; r++)
                acc[r] = fmaf(a_lds[r * D_FEAT + k], wk, acc[r]);
        }
    }
    #pragma unroll
    for (int r = 0; r < 16; r++)
        io[(size_t)(r0 + r) * D_FEAT + c] = acc[r];
}

// ---------------------------------------------------------------------------
extern "C" void kernel_launch(void* const* d_in, const int* in_sizes, int n_in,
                              void* d_out, int out_size, void* d_ws, size_t ws_size,
                              hipStream_t stream) {
    const void* x  = d_in[0];                    // f32 (detected) [N, 256]
    const void* ei = d_in[1];                    // int32 (detected) [2, E]
    const void* w  = d_in[2];                    // f32 (detected) [256, 256]
    float* out = (float*)d_out;                  // FLOAT32 [N, 256]
    uint8_t* ws = (uint8_t*)d_ws;

    // ---- primary plan: global bitmap (needs ~12.85 MB of ws) ----
    const size_t BM_BYTES   = (size_t)N_NODES * ROW_STRIDE * 4;   // 12,800,000
    const size_t DINV_OFF   = BM_BYTES;                            // 40,000 B
    const size_t FLAGS_OFF  = BM_BYTES + 40960;
    const size_t NEED_BM    = FLAGS_OFF + 256;

    // ---- fallback plan: CSR (needs ~2.86 MB of ws) ----
    const size_t NEED_CSR = (size_t)295168 + (size_t)2 * E_EDGES * 4;

    if (ws_size >= NEED_BM) {
        uint32_t* bitmap = (uint32_t*)ws;
        float*    dinv   = (float*)(ws + DINV_OFF);
        uint32_t* flags  = (uint32_t*)(ws + FLAGS_OFF);

        hipMemsetAsync(bitmap, 0, BM_BYTES, stream);
        detect_modes<<<1, 256, 0, stream>>>((const uint32_t*)x, (const uint32_t*)ei, flags);
        scatter_edges<<<(E_EDGES + 255) / 256, 256, 0, stream>>>(ei, flags, bitmap);
        popc_dinv   <<<N_NODES / 4, 256, 0, stream>>>(bitmap, dinv);
        spmm_bitmap <<<N_NODES / 4, 256, 0, stream>>>(bitmap, dinv, x, flags, out);
        gemm_valu   <<<N_NODES / 16, 256, 0, stream>>>(out, w, flags);
    } else if (ws_size >= NEED_CSR) {
        uint32_t* off   = (uint32_t*)(ws);
        uint32_t* cur   = (uint32_t*)(ws + 40960);
        uint32_t* degu  = (uint32_t*)(ws + 81920);
        float*    dinv  = (float*)   (ws + 122880);
        uint32_t* flags = (uint32_t*)(ws + 163840);
        uint32_t* col   = (uint32_t*)(ws + 295168);

        hipMemsetAsync(cur, 0, (size_t)N_NODES * 4, stream);
        detect_modes<<<1, 256, 0, stream>>>((const uint32_t*)x, (const uint32_t*)ei, flags);
        count_edges <<<(E_EDGES + 255) / 256, 256, 0, stream>>>(ei, flags, cur);
        scan_offsets<<<1, 256, 0, stream>>>(cur, off);
        init_cur    <<<(N_NODES + 255) / 256, 256, 0, stream>>>(off, cur);
        fill_edges  <<<(E_EDGES + 255) / 256, 256, 0, stream>>>(ei, flags, cur, col);
        dedup_rows  <<<N_NODES, 320, 0, stream>>>(off, col, degu, dinv);
        spmm_agg    <<<N_NODES / 2, 128, 0, stream>>>(off, col, degu, dinv, x, flags, out);
        gemm_valu   <<<N_NODES / 16, 256, 0, stream>>>(out, w, flags);
    }
    // else: ws too small for any plan — cannot compute without OOB; no-op.
}